// Round 1
// 1333.843 us; speedup vs baseline: 1.0714x; 1.0714x over previous
//
#include <hip/hip_runtime.h>
#include <hip/hip_bf16.h>
#include <stdint.h>

#define DM 2048
#define DF 8192
#define NT 8192

typedef unsigned short u16;
typedef __attribute__((ext_vector_type(8))) __bf16 bf16x8;
typedef __attribute__((ext_vector_type(4))) float f32x4;

typedef __attribute__((address_space(1))) uint8_t ga_u8_t;
typedef __attribute__((address_space(3))) uint8_t lds_u8_t;

__device__ __forceinline__ void async_cp16(const void* g, void* l) {
  __builtin_amdgcn_global_load_lds((ga_u8_t*)g, (lds_u8_t*)l, 16, 0, 0);
}

__device__ __forceinline__ u16 f2b(float f) {
  unsigned int u = __builtin_bit_cast(unsigned int, f);
  u = (u + 0x7fffu + ((u >> 16) & 1u)) >> 16;
  return (u16)u;
}
__device__ __forceinline__ float gelu_f(float x) {
  return 0.5f * x * (1.0f + erff(x * 0.70710678118654752f));
}

// -------- per-token combined gate weights: wtok[t] = (w0_eff, w1_eff) --------
__global__ void prep_wtok(const int* __restrict__ eid, const float* __restrict__ w,
                          float2* __restrict__ wtok, int n) {
  int i = blockIdx.x * blockDim.x + threadIdx.x;
  if (i >= n) return;
  float a = 0.f, b = 0.f;
  int e0 = eid[2 * i] & 1, e1 = eid[2 * i + 1] & 1;
  float w0 = w[2 * i], w1 = w[2 * i + 1];
  if (e0) b += w0; else a += w0;
  if (e1) b += w1; else a += w1;
  wtok[i] = make_float2(a, b);
}

// -------- fp32 -> bf16 elementwise (x -> Xb) --------
__global__ void conv_f32_bf16(const float* __restrict__ in, u16* __restrict__ out,
                              int n4) {
  int i = blockIdx.x * blockDim.x + threadIdx.x;
  if (i >= n4) return;
  float4 v = reinterpret_cast<const float4*>(in)[i];
  ushort4 o;
  o.x = f2b(v.x); o.y = f2b(v.y); o.z = f2b(v.z); o.w = f2b(v.w);
  reinterpret_cast<ushort4*>(out)[i] = o;
}

// -------- fp32 transpose+convert: in (R x Cc) fp32 -> out (Cc x R) bf16 --------
__global__ void transpose_conv(const float* __restrict__ in, u16* __restrict__ out,
                               int R, int Cc) {
  __shared__ float tile[32][33];
  int tx = threadIdx.x & 31, ty = threadIdx.x >> 5;  // 256 threads: 32x8
  int r0 = blockIdx.y * 32, c0 = blockIdx.x * 32;
#pragma unroll
  for (int i = 0; i < 32; i += 8)
    tile[ty + i][tx] = in[(size_t)(r0 + ty + i) * Cc + c0 + tx];
  __syncthreads();
#pragma unroll
  for (int i = 0; i < 32; i += 8)
    out[(size_t)(c0 + ty + i) * R + r0 + tx] = f2b(tile[tx][ty + i]);
}

__global__ void fill_sentinel(float* p, int n) {
  int i = blockIdx.x * blockDim.x + threadIdx.x;
  if (i < n) p[i] = 0.125f;
}

// ============================================================================
// 256x256-tile, BK=64, 8-wave (2Mx4N), 4-phase-per-K-tile GEMM (T3+T4+T5).
// C = A(MxK) @ Bt(NxK)^T, bf16 in, fp32 accum.
// MODE 0: C(bf16) = bf16( gelu(acc + bias[col]) * w_eff[t] )   (GEMM1 -> H)
// MODE 1: C(f32)  = acc + w_eff[t]*bias[col]                   (GEMM2, expert 0)
// MODE 2: C(f32) += acc + w_eff[t]*bias[col]                   (GEMM2, expert 1)
//
// LDS 128 KiB = 2 buffers x (A 32K | B 32K). Per wave: 128x64 output =
// acc[8][4] f32x4. Per phase: {ds_read subtile, stage 1 half-tile (2x
// global_load_lds/thread), barrier, lgkmcnt(0), prio1, 16 MFMA, prio0,
// barrier}. Counted s_waitcnt vmcnt(4) once per K-tile (2 half-tiles stay in
// flight) -- never drained to 0 in the main loop. Prefetch depth: A-halves of
// tile t+1 issued at t.ph0/ph1 (A region released at prev-tile ph2 end-bar);
// B-halves of tile t+2 issued at t.ph2/ph3 (B region released at ph1 end-bar).
// Staging swizzle (slot p holds k-group p^(row&7)) identical to the proven
// 128^2 kernel -> ds_read_b128 fragments conflict-free (measured 0).
// ============================================================================
template <int MODE>
__global__ __launch_bounds__(512, 2)
void gemm_bt(const u16* __restrict__ A, const u16* __restrict__ Bt,
             void* __restrict__ Cv, const float2* __restrict__ wtok,
             const float* __restrict__ bias,
             int M, int N, int K, int sel) {
  __shared__ __align__(16) char smem[131072];
  const int tid = threadIdx.x;
  const int w = tid >> 6;
  const int lane = tid & 63;

  // ---- bijective XCD swizzle (all our grids have nwg % 8 == 0) ----
  const int nwg = gridDim.x * gridDim.y;
  const int wg = blockIdx.y * gridDim.x + blockIdx.x;
  const int swz = (wg & 7) * (nwg >> 3) + (wg >> 3);
  const int bx = swz % gridDim.x;
  const int by = swz / gridDim.x;
  const int m0 = by * 256;
  const int n0 = bx * 256;
  const int NKT = K >> 6;

  // ---- staging addresses: wave-uniform LDS base + lane*16 (m104) ----
  const int r8 = lane >> 3, p8 = lane & 7, q = p8 ^ r8;
  const u16* gA[2];
  const u16* gB[2];
  int ldsOff[2];
#pragma unroll
  for (int j = 0; j < 2; ++j) {
    const int c = j * 8 + w;          // chunk 0..15 within a 128-row half
    const int row = c * 8 + r8;
    gA[j] = A + (size_t)(m0 + row) * K + q * 8;
    gB[j] = Bt + (size_t)(n0 + row) * K + q * 8;
    ldsOff[j] = c * 1024;
  }
  const size_t hstep = (size_t)128 * K;

  auto stA = [&](int kt, int h, int bp) {
    char* d = smem + bp * 65536 + h * 16384;
    const size_t go = (size_t)h * hstep + (size_t)kt * 64;
    async_cp16(gA[0] + go, d + ldsOff[0]);
    async_cp16(gA[1] + go, d + ldsOff[1]);
  };
  auto stB = [&](int kt, int h, int bp) {
    char* d = smem + 32768 + bp * 65536 + h * 16384;
    const size_t go = (size_t)h * hstep + (size_t)kt * 64;
    async_cp16(gB[0] + go, d + ldsOff[0]);
    async_cp16(gB[1] + go, d + ldsOff[1]);
  };

  // ---- fragment read bases (kk=1 is addr ^ 64: slot bit2 == logical k+4) --
  const int fr = lane & 15, qw = lane >> 4;
  const int wr = w >> 2, wc = w & 3;     // wave -> 128x64 output sub-tile
  const int sw = (qw ^ (fr & 7)) << 4;
  const uint32_t aBase = (uint32_t)((wr * 128 + fr) * 128 + sw);
  const uint32_t bBase = (uint32_t)(32768 + (wc * 64 + fr) * 128 + sw);

  auto ldf = [&](const char* base, uint32_t off) {
    return *reinterpret_cast<const bf16x8*>(base + off);
  };

  f32x4 acc[8][4] = {};
  bf16x8 af[4][2], bq[4][2];

  // ---- prologue: tile0 fully + tile1 B-halves; counted wait (never 0) ----
  stA(0, 0, 0); stA(0, 1, 0);
  stB(0, 0, 0); stB(0, 1, 0);
  stB(1, 0, 1); stB(1, 1, 1);
  asm volatile("s_waitcnt vmcnt(4)" ::: "memory");
  __builtin_amdgcn_s_barrier();

  for (int t = 0; t < NKT; ++t) {
    const int bp = t & 1;
    const char* Ab = smem + bp * 65536;
    const int kt1 = (t + 1 < NKT) ? t + 1 : NKT - 1;  // clamp: keeps issue
    const int kt2 = (t + 2 < NKT) ? t + 2 : NKT - 1;  // count & vmcnt uniform

    // ---------------- phase 0: a[0..3], b[0..1]; stage t+1 A-half0 --------
#pragma unroll
    for (int i = 0; i < 4; ++i) {
      af[i][0] = ldf(Ab, aBase + i * 2048);
      af[i][1] = ldf(Ab, (aBase + i * 2048) ^ 64u);
    }
#pragma unroll
    for (int j = 0; j < 2; ++j) {
      bq[j][0] = ldf(Ab, bBase + j * 2048);
      bq[j][1] = ldf(Ab, (bBase + j * 2048) ^ 64u);
    }
    stA(kt1, 0, bp ^ 1);
    __builtin_amdgcn_sched_barrier(0);
    __builtin_amdgcn_s_barrier();
    asm volatile("s_waitcnt lgkmcnt(0)" ::: "memory");
    __builtin_amdgcn_sched_barrier(0);
    __builtin_amdgcn_s_setprio(1);
#pragma unroll
    for (int kk = 0; kk < 2; ++kk)
#pragma unroll
      for (int i = 0; i < 4; ++i)
#pragma unroll
        for (int j = 0; j < 2; ++j)
          acc[i][j] = __builtin_amdgcn_mfma_f32_16x16x32_bf16(
              bq[j][kk], af[i][kk], acc[i][j], 0, 0, 0);
    __builtin_amdgcn_s_setprio(0);
    __builtin_amdgcn_sched_barrier(0);
    __builtin_amdgcn_s_barrier();

    // ---------------- phase 1: b[2..3]; stage t+1 A-half1 -----------------
#pragma unroll
    for (int j = 2; j < 4; ++j) {
      bq[j][0] = ldf(Ab, bBase + j * 2048);
      bq[j][1] = ldf(Ab, (bBase + j * 2048) ^ 64u);
    }
    stA(kt1, 1, bp ^ 1);
    __builtin_amdgcn_sched_barrier(0);
    __builtin_amdgcn_s_barrier();
    asm volatile("s_waitcnt lgkmcnt(0)" ::: "memory");
    __builtin_amdgcn_sched_barrier(0);
    __builtin_amdgcn_s_setprio(1);
#pragma unroll
    for (int kk = 0; kk < 2; ++kk)
#pragma unroll
      for (int i = 0; i < 4; ++i)
#pragma unroll
        for (int j = 2; j < 4; ++j)
          acc[i][j] = __builtin_amdgcn_mfma_f32_16x16x32_bf16(
              bq[j][kk], af[i][kk], acc[i][j], 0, 0, 0);
    __builtin_amdgcn_s_setprio(0);
    __builtin_amdgcn_sched_barrier(0);
    __builtin_amdgcn_s_barrier();
    // B region of buf[bp] fully consumed here -> t+2 B staging below is safe.

    // ---------------- phase 2: a[4..7]; stage t+2 B-half0 -----------------
#pragma unroll
    for (int i = 0; i < 4; ++i) {
      af[i][0] = ldf(Ab, aBase + (i + 4) * 2048);
      af[i][1] = ldf(Ab, (aBase + (i + 4) * 2048) ^ 64u);
    }
    stB(kt2, 0, bp);
    __builtin_amdgcn_sched_barrier(0);
    __builtin_amdgcn_s_barrier();
    asm volatile("s_waitcnt lgkmcnt(0)" ::: "memory");
    __builtin_amdgcn_sched_barrier(0);
    __builtin_amdgcn_s_setprio(1);
#pragma unroll
    for (int kk = 0; kk < 2; ++kk)
#pragma unroll
      for (int i = 0; i < 4; ++i)
#pragma unroll
        for (int j = 2; j < 4; ++j)
          acc[i + 4][j] = __builtin_amdgcn_mfma_f32_16x16x32_bf16(
              bq[j][kk], af[i][kk], acc[i + 4][j], 0, 0, 0);
    __builtin_amdgcn_s_setprio(0);
    __builtin_amdgcn_sched_barrier(0);
    __builtin_amdgcn_s_barrier();
    // A region of buf[bp] fully consumed here (next-tile A was staged ph0/1
    // into the OTHER buffer; t+2's A goes out during tile t+1's ph0/1).

    // ---------------- phase 3: no reads; stage t+2 B-half1; counted wait --
    stB(kt2, 1, bp);
    __builtin_amdgcn_sched_barrier(0);
    __builtin_amdgcn_s_setprio(1);
#pragma unroll
    for (int kk = 0; kk < 2; ++kk)
#pragma unroll
      for (int i = 0; i < 4; ++i)
#pragma unroll
        for (int j = 0; j < 2; ++j)
          acc[i + 4][j] = __builtin_amdgcn_mfma_f32_16x16x32_bf16(
              bq[j][kk], af[i][kk], acc[i + 4][j], 0, 0, 0);
    __builtin_amdgcn_s_setprio(0);
    __builtin_amdgcn_sched_barrier(0);
    // Tile t+1 fully landed once all-but-4 loads retire (the 4 newest =
    // t+2's B0,B1 stay in flight across the barrier).
    asm volatile("s_waitcnt vmcnt(4)" ::: "memory");
    __builtin_amdgcn_sched_barrier(0);
    __builtin_amdgcn_s_barrier();
  }
  asm volatile("s_waitcnt vmcnt(0)" ::: "memory");  // drain before exit

  // ---- epilogue (mapping identical to proven 128^2 kernel) ----
#pragma unroll
  for (int i = 0; i < 8; ++i) {
    const int trow = m0 + wr * 128 + i * 16 + fr;
    const float2 wt = wtok[trow];
    const float ws = sel ? wt.y : wt.x;
#pragma unroll
    for (int j = 0; j < 4; ++j) {
      const int col0 = n0 + wc * 64 + j * 16 + qw * 4;
      const float4 bb = *reinterpret_cast<const float4*>(bias + col0);
      f32x4 a = acc[i][j];
      if (MODE == 0) {
        u16* C = (u16*)Cv;
        ushort4 o;
        o.x = f2b(gelu_f(a.x + bb.x) * ws);
        o.y = f2b(gelu_f(a.y + bb.y) * ws);
        o.z = f2b(gelu_f(a.z + bb.z) * ws);
        o.w = f2b(gelu_f(a.w + bb.w) * ws);
        *reinterpret_cast<ushort4*>(C + (size_t)trow * N + col0) = o;
      } else {
        float* C = (float*)Cv;
        float4 o;
        o.x = a.x + ws * bb.x;
        o.y = a.y + ws * bb.y;
        o.z = a.z + ws * bb.z;
        o.w = a.w + ws * bb.w;
        if (MODE == 2) {
          float4 pv = *reinterpret_cast<const float4*>(C + (size_t)trow * N + col0);
          o.x += pv.x; o.y += pv.y; o.z += pv.z; o.w += pv.w;
        }
        *reinterpret_cast<float4*>(C + (size_t)trow * N + col0) = o;
      }
    }
  }
}

extern "C" void kernel_launch(void* const* d_in, const int* in_sizes, int n_in,
                              void* d_out, int out_size, void* d_ws, size_t ws_size,
                              hipStream_t stream) {
  const float* x    = (const float*)d_in[0];
  const int*   eid  = (const int*)d_in[1];
  const float* topw = (const float*)d_in[2];
  const float* W1_0 = (const float*)d_in[3];
  const float* b1_0 = (const float*)d_in[4];
  const float* W2_0 = (const float*)d_in[5];
  const float* b2_0 = (const float*)d_in[6];
  const float* W1_1 = (const float*)d_in[7];
  const float* b1_1 = (const float*)d_in[8];
  const float* W2_1 = (const float*)d_in[9];
  const float* b2_1 = (const float*)d_in[10];
  float* out = (float*)d_out;

  char* ws = (char*)d_ws;
  const size_t SZ_WT = (size_t)DM * DF * sizeof(u16);  // 32 MiB
  size_t off = (size_t)NT * sizeof(float2);            // 64 KiB
  float2* wtok = (float2*)ws;
  u16* Xb  = (u16*)(ws + off); off += (size_t)NT * DM * sizeof(u16);  // 32 MiB
  u16* WTa = (u16*)(ws + off); off += SZ_WT;                           // 32 MiB
  u16* WTb = (u16*)(ws + off); off += SZ_WT;                           // 32 MiB
  u16* H   = (u16*)(ws + off); off += (size_t)NT * DF * sizeof(u16);  // 128 MiB

  if (ws_size < off) {
    fill_sentinel<<<(out_size + 255) / 256, 256, 0, stream>>>(out, out_size);
    return;
  }

  prep_wtok<<<(NT + 255) / 256, 256, 0, stream>>>(eid, topw, wtok, NT);
  conv_f32_bf16<<<(NT * DM / 4 + 255) / 256, 256, 0, stream>>>(x, Xb, NT * DM / 4);

  dim3 g1(DF / 256, NT / 256);  // (32, 32) = 1024 wg -> 4 clean rounds @1/CU
  dim3 g2(DM / 256, NT / 256);  // (8, 32)  = 256 wg  -> 1 clean round

  // expert 0
  transpose_conv<<<dim3(DF / 32, DM / 32), 256, 0, stream>>>(W1_0, WTa, DM, DF);
  gemm_bt<0><<<g1, 512, 0, stream>>>(Xb, WTa, H, wtok, b1_0, NT, DF, DM, 0);
  transpose_conv<<<dim3(DM / 32, DF / 32), 256, 0, stream>>>(W2_0, WTb, DF, DM);
  gemm_bt<1><<<g2, 512, 0, stream>>>(H, WTb, out, wtok, b2_0, NT, DM, DF, 0);
  // expert 1
  transpose_conv<<<dim3(DF / 32, DM / 32), 256, 0, stream>>>(W1_1, WTa, DM, DF);
  gemm_bt<0><<<g1, 512, 0, stream>>>(Xb, WTa, H, wtok, b1_1, NT, DF, DM, 1);
  transpose_conv<<<dim3(DM / 32, DF / 32), 256, 0, stream>>>(W2_1, WTb, DF, DM);
  gemm_bt<2><<<g2, 512, 0, stream>>>(H, WTb, out, wtok, b2_1, NT, DM, DF, 1);
}

// Round 2
// 1259.021 us; speedup vs baseline: 1.1351x; 1.0594x over previous
//
#include <hip/hip_runtime.h>
#include <hip/hip_bf16.h>
#include <stdint.h>

#define DM 2048
#define DF 8192
#define NT 8192

typedef unsigned short u16;
typedef __attribute__((ext_vector_type(8))) __bf16 bf16x8;
typedef __attribute__((ext_vector_type(4))) float f32x4;

typedef __attribute__((address_space(1))) uint8_t ga_u8_t;
typedef __attribute__((address_space(3))) uint8_t lds_u8_t;

__device__ __forceinline__ void async_cp16(const void* g, void* l) {
  __builtin_amdgcn_global_load_lds((ga_u8_t*)g, (lds_u8_t*)l, 16, 0, 0);
}

__device__ __forceinline__ u16 f2b(float f) {
  unsigned int u = __builtin_bit_cast(unsigned int, f);
  u = (u + 0x7fffu + ((u >> 16) & 1u)) >> 16;
  return (u16)u;
}

// Branch-free erf (Abramowitz-Stegun 7.1.26, |err|<=1.5e-7): ~14 VALU inst
// vs libm erff's branchy ~40. H is bf16-rounded anyway (rel 2^-9), so 1.5e-7
// absolute is invisible. v_rcp_f32 + v_exp_f32, no divergence.
__device__ __forceinline__ float erf_fast(float z) {
  float az = fabsf(z);
  float t = __builtin_amdgcn_rcpf(fmaf(0.3275911f, az, 1.0f));
  float p = t * fmaf(t, fmaf(t, fmaf(t, fmaf(t, 1.061405429f, -1.453152027f),
                                     1.421413741f), -0.284496736f),
                     0.254829592f);
  float r = fmaf(-p, __expf(-az * az), 1.0f);
  return copysignf(r, z);
}
__device__ __forceinline__ float gelu_f(float x) {
  return 0.5f * x * (1.0f + erf_fast(x * 0.70710678118654752f));
}

// -------- per-token combined gate weights: wtok[t] = (w0_eff, w1_eff) --------
__global__ void prep_wtok(const int* __restrict__ eid, const float* __restrict__ w,
                          float2* __restrict__ wtok, int n) {
  int i = blockIdx.x * blockDim.x + threadIdx.x;
  if (i >= n) return;
  float a = 0.f, b = 0.f;
  int e0 = eid[2 * i] & 1, e1 = eid[2 * i + 1] & 1;
  float w0 = w[2 * i], w1 = w[2 * i + 1];
  if (e0) b += w0; else a += w0;
  if (e1) b += w1; else a += w1;
  wtok[i] = make_float2(a, b);
}

// -------- fp32 -> bf16 elementwise (x -> Xb) --------
__global__ void conv_f32_bf16(const float* __restrict__ in, u16* __restrict__ out,
                              int n4) {
  int i = blockIdx.x * blockDim.x + threadIdx.x;
  if (i >= n4) return;
  float4 v = reinterpret_cast<const float4*>(in)[i];
  ushort4 o;
  o.x = f2b(v.x); o.y = f2b(v.y); o.z = f2b(v.z); o.w = f2b(v.w);
  reinterpret_cast<ushort4*>(out)[i] = o;
}

// -------- fp32 transpose+convert: in (R x Cc) fp32 -> out (Cc x R) bf16 --------
__global__ void transpose_conv(const float* __restrict__ in, u16* __restrict__ out,
                               int R, int Cc) {
  __shared__ float tile[32][33];
  int tx = threadIdx.x & 31, ty = threadIdx.x >> 5;  // 256 threads: 32x8
  int r0 = blockIdx.y * 32, c0 = blockIdx.x * 32;
#pragma unroll
  for (int i = 0; i < 32; i += 8)
    tile[ty + i][tx] = in[(size_t)(r0 + ty + i) * Cc + c0 + tx];
  __syncthreads();
#pragma unroll
  for (int i = 0; i < 32; i += 8)
    out[(size_t)(c0 + ty + i) * R + r0 + tx] = f2b(tile[tx][ty + i]);
}

__global__ void fill_sentinel(float* p, int n) {
  int i = blockIdx.x * blockDim.x + threadIdx.x;
  if (i < n) p[i] = 0.125f;
}

// ============================================================================
// 256x256-tile, BK=64, 8-wave (2Mx4N), 4-phase GEMM -- 2 barriers per K-tile.
// C = A(MxK) @ Bt(NxK)^T, bf16 in, fp32 accum.
// MODE 0: C(bf16) = bf16( gelu(acc + bias[col]) * w_eff[t] )   (GEMM1 -> H)
// MODE 1: C(f32)  = acc + w_eff[t]*bias[col]                   (GEMM2, expert 0)
// MODE 2: C(f32) += acc + w_eff[t]*bias[col]                   (GEMM2, expert 1)
//
// R1 change: dropped the 6 lockstep barriers per K-tile; kept only the two
// DATA-required ones:
//   mid-tile  (after ph1 MFMA): all waves' B-reads of buf[bp] done before
//             ph2/ph3's stB overwrites buf[bp].B with tile t+2's data.
//   tile-end  (vmcnt(4) + barrier): tile t+1's A+B landed (the 4 newest
//             outstanding loads = t+2's B stay in flight); also gates next
//             tile's stA into buf[bp^1] vs its last readers (prev tile ph2).
// Waves now drift between barriers: one wave's ds_reads overlap its
// SIMD-mate's MFMA cluster (setprio arbitrates) instead of all waves idling
// the matrix pipe in lockstep. lgkmcnt(0)+sched_barrier(0) before each MFMA
// cluster retained (rule #18). bq/af live in registers, so LDS overwrites
// by stB never touch in-flight operands.
// ============================================================================
template <int MODE>
__global__ __launch_bounds__(512, 2)
void gemm_bt(const u16* __restrict__ A, const u16* __restrict__ Bt,
             void* __restrict__ Cv, const float2* __restrict__ wtok,
             const float* __restrict__ bias,
             int M, int N, int K, int sel) {
  __shared__ __align__(16) char smem[131072];
  const int tid = threadIdx.x;
  const int w = tid >> 6;
  const int lane = tid & 63;

  // ---- bijective XCD swizzle (all our grids have nwg % 8 == 0) ----
  const int nwg = gridDim.x * gridDim.y;
  const int wg = blockIdx.y * gridDim.x + blockIdx.x;
  const int swz = (wg & 7) * (nwg >> 3) + (wg >> 3);
  const int bx = swz % gridDim.x;
  const int by = swz / gridDim.x;
  const int m0 = by * 256;
  const int n0 = bx * 256;
  const int NKT = K >> 6;

  // ---- staging addresses: wave-uniform LDS base + lane*16 (m104) ----
  const int r8 = lane >> 3, p8 = lane & 7, q = p8 ^ r8;
  const u16* gA[2];
  const u16* gB[2];
  int ldsOff[2];
#pragma unroll
  for (int j = 0; j < 2; ++j) {
    const int c = j * 8 + w;          // chunk 0..15 within a 128-row half
    const int row = c * 8 + r8;
    gA[j] = A + (size_t)(m0 + row) * K + q * 8;
    gB[j] = Bt + (size_t)(n0 + row) * K + q * 8;
    ldsOff[j] = c * 1024;
  }
  const size_t hstep = (size_t)128 * K;

  auto stA = [&](int kt, int h, int bp) {
    char* d = smem + bp * 65536 + h * 16384;
    const size_t go = (size_t)h * hstep + (size_t)kt * 64;
    async_cp16(gA[0] + go, d + ldsOff[0]);
    async_cp16(gA[1] + go, d + ldsOff[1]);
  };
  auto stB = [&](int kt, int h, int bp) {
    char* d = smem + 32768 + bp * 65536 + h * 16384;
    const size_t go = (size_t)h * hstep + (size_t)kt * 64;
    async_cp16(gB[0] + go, d + ldsOff[0]);
    async_cp16(gB[1] + go, d + ldsOff[1]);
  };

  // ---- fragment read bases (kk=1 is addr ^ 64: slot bit2 == logical k+4) --
  const int fr = lane & 15, qw = lane >> 4;
  const int wr = w >> 2, wc = w & 3;     // wave -> 128x64 output sub-tile
  const int sw = (qw ^ (fr & 7)) << 4;
  const uint32_t aBase = (uint32_t)((wr * 128 + fr) * 128 + sw);
  const uint32_t bBase = (uint32_t)(32768 + (wc * 64 + fr) * 128 + sw);

  auto ldf = [&](const char* base, uint32_t off) {
    return *reinterpret_cast<const bf16x8*>(base + off);
  };

  f32x4 acc[8][4] = {};
  bf16x8 af[4][2], bq[4][2];

  // ---- prologue: tile0 fully + tile1 B-halves; counted wait (never 0) ----
  stA(0, 0, 0); stA(0, 1, 0);
  stB(0, 0, 0); stB(0, 1, 0);
  stB(1, 0, 1); stB(1, 1, 1);
  asm volatile("s_waitcnt vmcnt(4)" ::: "memory");
  __builtin_amdgcn_s_barrier();

  for (int t = 0; t < NKT; ++t) {
    const int bp = t & 1;
    const char* Ab = smem + bp * 65536;
    const int kt1 = (t + 1 < NKT) ? t + 1 : NKT - 1;  // clamp: keeps issue
    const int kt2 = (t + 2 < NKT) ? t + 2 : NKT - 1;  // count & vmcnt uniform

    // ---- phase 0: a[0..3], b[0..1]; stage t+1 A-half0 ----
#pragma unroll
    for (int i = 0; i < 4; ++i) {
      af[i][0] = ldf(Ab, aBase + i * 2048);
      af[i][1] = ldf(Ab, (aBase + i * 2048) ^ 64u);
    }
#pragma unroll
    for (int j = 0; j < 2; ++j) {
      bq[j][0] = ldf(Ab, bBase + j * 2048);
      bq[j][1] = ldf(Ab, (bBase + j * 2048) ^ 64u);
    }
    stA(kt1, 0, bp ^ 1);
    asm volatile("s_waitcnt lgkmcnt(0)" ::: "memory");
    __builtin_amdgcn_sched_barrier(0);
    __builtin_amdgcn_s_setprio(1);
#pragma unroll
    for (int kk = 0; kk < 2; ++kk)
#pragma unroll
      for (int i = 0; i < 4; ++i)
#pragma unroll
        for (int j = 0; j < 2; ++j)
          acc[i][j] = __builtin_amdgcn_mfma_f32_16x16x32_bf16(
              bq[j][kk], af[i][kk], acc[i][j], 0, 0, 0);
    __builtin_amdgcn_s_setprio(0);

    // ---- phase 1: b[2..3]; stage t+1 A-half1 ----
#pragma unroll
    for (int j = 2; j < 4; ++j) {
      bq[j][0] = ldf(Ab, bBase + j * 2048);
      bq[j][1] = ldf(Ab, (bBase + j * 2048) ^ 64u);
    }
    stA(kt1, 1, bp ^ 1);
    asm volatile("s_waitcnt lgkmcnt(0)" ::: "memory");
    __builtin_amdgcn_sched_barrier(0);
    __builtin_amdgcn_s_setprio(1);
#pragma unroll
    for (int kk = 0; kk < 2; ++kk)
#pragma unroll
      for (int i = 0; i < 4; ++i)
#pragma unroll
        for (int j = 2; j < 4; ++j)
          acc[i][j] = __builtin_amdgcn_mfma_f32_16x16x32_bf16(
              bq[j][kk], af[i][kk], acc[i][j], 0, 0, 0);
    __builtin_amdgcn_s_setprio(0);
    // B region of buf[bp] fully read by ALL waves after this barrier ->
    // ph2/ph3's stB may overwrite it.
    __builtin_amdgcn_s_barrier();
    __builtin_amdgcn_sched_barrier(0);

    // ---- phase 2: a[4..7]; stage t+2 B-half0 ----
#pragma unroll
    for (int i = 0; i < 4; ++i) {
      af[i][0] = ldf(Ab, aBase + (i + 4) * 2048);
      af[i][1] = ldf(Ab, (aBase + (i + 4) * 2048) ^ 64u);
    }
    stB(kt2, 0, bp);
    asm volatile("s_waitcnt lgkmcnt(0)" ::: "memory");
    __builtin_amdgcn_sched_barrier(0);
    __builtin_amdgcn_s_setprio(1);
#pragma unroll
    for (int kk = 0; kk < 2; ++kk)
#pragma unroll
      for (int i = 0; i < 4; ++i)
#pragma unroll
        for (int j = 2; j < 4; ++j)
          acc[i + 4][j] = __builtin_amdgcn_mfma_f32_16x16x32_bf16(
              bq[j][kk], af[i][kk], acc[i + 4][j], 0, 0, 0);
    __builtin_amdgcn_s_setprio(0);

    // ---- phase 3: no reads; stage t+2 B-half1; counted wait ----
    stB(kt2, 1, bp);
    __builtin_amdgcn_s_setprio(1);
#pragma unroll
    for (int kk = 0; kk < 2; ++kk)
#pragma unroll
      for (int i = 0; i < 4; ++i)
#pragma unroll
        for (int j = 0; j < 2; ++j)
          acc[i + 4][j] = __builtin_amdgcn_mfma_f32_16x16x32_bf16(
              bq[j][kk], af[i][kk], acc[i + 4][j], 0, 0, 0);
    __builtin_amdgcn_s_setprio(0);
    // Tile t+1 fully landed once all-but-4 loads retire (the 4 newest =
    // t+2's B0,B1 stay in flight across the barrier).
    asm volatile("s_waitcnt vmcnt(4)" ::: "memory");
    __builtin_amdgcn_s_barrier();
    __builtin_amdgcn_sched_barrier(0);
  }
  asm volatile("s_waitcnt vmcnt(0)" ::: "memory");  // drain before exit

  // ---- epilogue ----
#pragma unroll
  for (int i = 0; i < 8; ++i) {
    const int trow = m0 + wr * 128 + i * 16 + fr;
    const float2 wt = wtok[trow];
    const float ws = sel ? wt.y : wt.x;
#pragma unroll
    for (int j = 0; j < 4; ++j) {
      const int col0 = n0 + wc * 64 + j * 16 + qw * 4;
      const float4 bb = *reinterpret_cast<const float4*>(bias + col0);
      f32x4 a = acc[i][j];
      if (MODE == 0) {
        u16* C = (u16*)Cv;
        ushort4 o;
        o.x = f2b(gelu_f(a.x + bb.x) * ws);
        o.y = f2b(gelu_f(a.y + bb.y) * ws);
        o.z = f2b(gelu_f(a.z + bb.z) * ws);
        o.w = f2b(gelu_f(a.w + bb.w) * ws);
        *reinterpret_cast<ushort4*>(C + (size_t)trow * N + col0) = o;
      } else {
        float* C = (float*)Cv;
        float4 o;
        o.x = a.x + ws * bb.x;
        o.y = a.y + ws * bb.y;
        o.z = a.z + ws * bb.z;
        o.w = a.w + ws * bb.w;
        if (MODE == 2) {
          float4 pv = *reinterpret_cast<const float4*>(C + (size_t)trow * N + col0);
          o.x += pv.x; o.y += pv.y; o.z += pv.z; o.w += pv.w;
        }
        *reinterpret_cast<float4*>(C + (size_t)trow * N + col0) = o;
      }
    }
  }
}

extern "C" void kernel_launch(void* const* d_in, const int* in_sizes, int n_in,
                              void* d_out, int out_size, void* d_ws, size_t ws_size,
                              hipStream_t stream) {
  const float* x    = (const float*)d_in[0];
  const int*   eid  = (const int*)d_in[1];
  const float* topw = (const float*)d_in[2];
  const float* W1_0 = (const float*)d_in[3];
  const float* b1_0 = (const float*)d_in[4];
  const float* W2_0 = (const float*)d_in[5];
  const float* b2_0 = (const float*)d_in[6];
  const float* W1_1 = (const float*)d_in[7];
  const float* b1_1 = (const float*)d_in[8];
  const float* W2_1 = (const float*)d_in[9];
  const float* b2_1 = (const float*)d_in[10];
  float* out = (float*)d_out;

  char* ws = (char*)d_ws;
  const size_t SZ_WT = (size_t)DM * DF * sizeof(u16);  // 32 MiB
  size_t off = (size_t)NT * sizeof(float2);            // 64 KiB
  float2* wtok = (float2*)ws;
  u16* Xb  = (u16*)(ws + off); off += (size_t)NT * DM * sizeof(u16);  // 32 MiB
  u16* WTa = (u16*)(ws + off); off += SZ_WT;                           // 32 MiB
  u16* WTb = (u16*)(ws + off); off += SZ_WT;                           // 32 MiB
  u16* H   = (u16*)(ws + off); off += (size_t)NT * DF * sizeof(u16);  // 128 MiB

  if (ws_size < off) {
    fill_sentinel<<<(out_size + 255) / 256, 256, 0, stream>>>(out, out_size);
    return;
  }

  prep_wtok<<<(NT + 255) / 256, 256, 0, stream>>>(eid, topw, wtok, NT);
  conv_f32_bf16<<<(NT * DM / 4 + 255) / 256, 256, 0, stream>>>(x, Xb, NT * DM / 4);

  dim3 g1(DF / 256, NT / 256);  // (32, 32) = 1024 wg -> 4 clean rounds @1/CU
  dim3 g2(DM / 256, NT / 256);  // (8, 32)  = 256 wg  -> 1 clean round

  // expert 0
  transpose_conv<<<dim3(DF / 32, DM / 32), 256, 0, stream>>>(W1_0, WTa, DM, DF);
  gemm_bt<0><<<g1, 512, 0, stream>>>(Xb, WTa, H, wtok, b1_0, NT, DF, DM, 0);
  transpose_conv<<<dim3(DM / 32, DF / 32), 256, 0, stream>>>(W2_0, WTb, DF, DM);
  gemm_bt<1><<<g2, 512, 0, stream>>>(H, WTb, out, wtok, b2_0, NT, DM, DF, 0);
  // expert 1
  transpose_conv<<<dim3(DF / 32, DM / 32), 256, 0, stream>>>(W1_1, WTa, DM, DF);
  gemm_bt<0><<<g1, 512, 0, stream>>>(Xb, WTa, H, wtok, b1_1, NT, DF, DM, 1);
  transpose_conv<<<dim3(DM / 32, DF / 32), 256, 0, stream>>>(W2_1, WTb, DF, DM);
  gemm_bt<2><<<g2, 512, 0, stream>>>(H, WTb, out, wtok, b2_1, NT, DM, DF, 1);
}

// Round 3
// 1238.988 us; speedup vs baseline: 1.1535x; 1.0162x over previous
//
#include <hip/hip_runtime.h>
#include <hip/hip_bf16.h>
#include <stdint.h>

#define DM 2048
#define DF 8192
#define NT 8192

typedef unsigned short u16;
typedef __attribute__((ext_vector_type(8))) __bf16 bf16x8;
typedef __attribute__((ext_vector_type(4))) float f32x4;

typedef __attribute__((address_space(1))) uint8_t ga_u8_t;
typedef __attribute__((address_space(3))) uint8_t lds_u8_t;

__device__ __forceinline__ void async_cp16(const void* g, void* l) {
  __builtin_amdgcn_global_load_lds((ga_u8_t*)g, (lds_u8_t*)l, 16, 0, 0);
}

__device__ __forceinline__ u16 f2b(float f) {
  unsigned int u = __builtin_bit_cast(unsigned int, f);
  u = (u + 0x7fffu + ((u >> 16) & 1u)) >> 16;
  return (u16)u;
}

// Branch-free erf (A&S 7.1.26, |err|<=1.5e-7). H is bf16-rounded (rel 2^-9),
// so the approximation error is invisible. ~14 VALU inst, no divergence.
__device__ __forceinline__ float erf_fast(float z) {
  float az = fabsf(z);
  float t = __builtin_amdgcn_rcpf(fmaf(0.3275911f, az, 1.0f));
  float p = t * fmaf(t, fmaf(t, fmaf(t, fmaf(t, 1.061405429f, -1.453152027f),
                                     1.421413741f), -0.284496736f),
                     0.254829592f);
  float r = fmaf(-p, __expf(-az * az), 1.0f);
  return copysignf(r, z);
}
__device__ __forceinline__ float gelu_f(float x) {
  return 0.5f * x * (1.0f + erf_fast(x * 0.70710678118654752f));
}

// -------- per-token combined gate weights: wtok[t] = (w0_eff, w1_eff) --------
__global__ void prep_wtok(const int* __restrict__ eid, const float* __restrict__ w,
                          float2* __restrict__ wtok, int n) {
  int i = blockIdx.x * blockDim.x + threadIdx.x;
  if (i >= n) return;
  float a = 0.f, b = 0.f;
  int e0 = eid[2 * i] & 1, e1 = eid[2 * i + 1] & 1;
  float w0 = w[2 * i], w1 = w[2 * i + 1];
  if (e0) b += w0; else a += w0;
  if (e1) b += w1; else a += w1;
  wtok[i] = make_float2(a, b);
}

// -------- fp32 -> bf16 elementwise (x -> Xb) --------
__global__ void conv_f32_bf16(const float* __restrict__ in, u16* __restrict__ out,
                              int n4) {
  int i = blockIdx.x * blockDim.x + threadIdx.x;
  if (i >= n4) return;
  float4 v = reinterpret_cast<const float4*>(in)[i];
  ushort4 o;
  o.x = f2b(v.x); o.y = f2b(v.y); o.z = f2b(v.z); o.w = f2b(v.w);
  reinterpret_cast<ushort4*>(out)[i] = o;
}

// -------- fp32 transpose+convert: in (R x Cc) fp32 -> out (Cc x R) bf16 -----
// R3: 64x64 tile, float4 global loads (256B/row-quad), ushort4 stores in
// 128B runs per 16 lanes. Replaces scalar 32x32 version (~2x BW).
__global__ void transpose_conv(const float* __restrict__ in, u16* __restrict__ out,
                               int R, int Cc) {
  __shared__ float tile[64][65];
  const int tid = threadIdx.x;          // 256 threads
  const int r0 = blockIdx.y * 64, c0 = blockIdx.x * 64;
  const int ty = tid >> 4;              // 0..15
  const int tx = (tid & 15) << 2;       // 0,4,..,60
#pragma unroll
  for (int i = 0; i < 4; ++i) {
    int r = ty + i * 16;
    float4 v = *reinterpret_cast<const float4*>(&in[(size_t)(r0 + r) * Cc + c0 + tx]);
    tile[r][tx] = v.x; tile[r][tx + 1] = v.y;
    tile[r][tx + 2] = v.z; tile[r][tx + 3] = v.w;
  }
  __syncthreads();
  const int rg = (tid & 15) << 2;       // output r = rg..rg+3
  const int cg = tid >> 4;              // output c = cg + 16*i
#pragma unroll
  for (int i = 0; i < 4; ++i) {
    int c = cg + 16 * i;
    ushort4 o;
    o.x = f2b(tile[rg + 0][c]);
    o.y = f2b(tile[rg + 1][c]);
    o.z = f2b(tile[rg + 2][c]);
    o.w = f2b(tile[rg + 3][c]);
    *reinterpret_cast<ushort4*>(&out[(size_t)(c0 + c) * R + r0 + rg]) = o;
  }
}

__global__ void fill_sentinel(float* p, int n) {
  int i = blockIdx.x * blockDim.x + threadIdx.x;
  if (i < n) p[i] = 0.125f;
}

// ============================================================================
// 256x256-tile, BK=64, 8-wave (2Mx4N) GEMM. 2 barriers/K-tile (drift), depth-2
// B prefetch, counted vmcnt(4). R3: k-split 4-phase schedule with ONE-GROUP-
// AHEAD ds_read prefetch and counted lgkmcnt waits -- removes 3 of 4 exposed
// LDS-latency drains per K-tile:
//   G0 {b_k0, aLo_k0} ; G1 {aHi_k0} ; stA(h0) ; lgkm(4)  -> P0: aLo*b_k0
//   G2 {b_k1, aLo_k1} ; stA(h1)     ;           lgkm(8)  -> P1: aHi*b_k0
//   G3 {aHi_k1}       ;               lgkm(4) ; BARRIER ; stB(h0)
//                                                        -> P2: aLo*b_k1
//   stB(h1)           ;               lgkm(0)            -> P3: aHi*b_k1
//   vmcnt(4) ; BARRIER
// DS ops retire FIFO; groups pinned with sched_barrier(0) so the counted
// waits are exact. Frag regs: b0,b1,aL,aH = 64 VGPR (same peak as R2; the
// k-halves are no longer co-resident, which funds the prefetch).
// MODE 0: C(bf16) = bf16( gelu(acc + bias[col]) * w_eff[t] )   (GEMM1 -> H)
// MODE 1: C(f32)  = acc + w_eff[t]*bias[col]                   (GEMM2, e0)
// MODE 2: C(f32) += acc + w_eff[t]*bias[col]                   (GEMM2, e1)
// ============================================================================
template <int MODE>
__global__ __launch_bounds__(512, 2)
void gemm_bt(const u16* __restrict__ A, const u16* __restrict__ Bt,
             void* __restrict__ Cv, const float2* __restrict__ wtok,
             const float* __restrict__ bias,
             int M, int N, int K, int sel) {
  __shared__ __align__(16) char smem[131072];
  const int tid = threadIdx.x;
  const int w = tid >> 6;
  const int lane = tid & 63;

  // ---- bijective XCD swizzle (all our grids have nwg % 8 == 0) ----
  const int nwg = gridDim.x * gridDim.y;
  const int wg = blockIdx.y * gridDim.x + blockIdx.x;
  const int swz = (wg & 7) * (nwg >> 3) + (wg >> 3);
  const int bx = swz % gridDim.x;
  const int by = swz / gridDim.x;
  const int m0 = by * 256;
  const int n0 = bx * 256;
  const int NKT = K >> 6;

  // ---- staging addresses: wave-uniform LDS base + lane*16 (m104) ----
  const int r8 = lane >> 3, p8 = lane & 7, q = p8 ^ r8;
  const u16* gA[2];
  const u16* gB[2];
  int ldsOff[2];
#pragma unroll
  for (int j = 0; j < 2; ++j) {
    const int c = j * 8 + w;          // chunk 0..15 within a 128-row half
    const int row = c * 8 + r8;
    gA[j] = A + (size_t)(m0 + row) * K + q * 8;
    gB[j] = Bt + (size_t)(n0 + row) * K + q * 8;
    ldsOff[j] = c * 1024;
  }
  const size_t hstep = (size_t)128 * K;

  auto stA = [&](int kt, int h, int bp) {
    char* d = smem + bp * 65536 + h * 16384;
    const size_t go = (size_t)h * hstep + (size_t)kt * 64;
    async_cp16(gA[0] + go, d + ldsOff[0]);
    async_cp16(gA[1] + go, d + ldsOff[1]);
  };
  auto stB = [&](int kt, int h, int bp) {
    char* d = smem + 32768 + bp * 65536 + h * 16384;
    const size_t go = (size_t)h * hstep + (size_t)kt * 64;
    async_cp16(gB[0] + go, d + ldsOff[0]);
    async_cp16(gB[1] + go, d + ldsOff[1]);
  };

  // ---- fragment read bases (k1 is addr ^ 64: slot bit2 == logical k+4) ----
  const int fr = lane & 15, qw = lane >> 4;
  const int wr = w >> 2, wc = w & 3;     // wave -> 128x64 output sub-tile
  const int sw = (qw ^ (fr & 7)) << 4;
  const uint32_t aBase = (uint32_t)((wr * 128 + fr) * 128 + sw);
  const uint32_t bBase = (uint32_t)(32768 + (wc * 64 + fr) * 128 + sw);

  auto ldf = [&](const char* base, uint32_t off) {
    return *reinterpret_cast<const bf16x8*>(base + off);
  };

  f32x4 acc[8][4] = {};
  bf16x8 aL[4], aH[4], b0[4], b1[4];

  // ---- prologue: tile0 fully + tile1 B-halves; counted wait (never 0) ----
  stA(0, 0, 0); stA(0, 1, 0);
  stB(0, 0, 0); stB(0, 1, 0);
  stB(1, 0, 1); stB(1, 1, 1);
  asm volatile("s_waitcnt vmcnt(4)" ::: "memory");
  __builtin_amdgcn_s_barrier();
  __builtin_amdgcn_sched_barrier(0);

  for (int t = 0; t < NKT; ++t) {
    const int bp = t & 1;
    const char* Ab = smem + bp * 65536;
    const int kt1 = (t + 1 < NKT) ? t + 1 : NKT - 1;  // clamp: keeps issue
    const int kt2 = (t + 2 < NKT) ? t + 2 : NKT - 1;  // count & vmcnt uniform

    // ---- G0: b_k0 (4) + aLo_k0 (4) ----
#pragma unroll
    for (int j = 0; j < 4; ++j) b0[j] = ldf(Ab, bBase + j * 2048);
#pragma unroll
    for (int i = 0; i < 4; ++i) aL[i] = ldf(Ab, aBase + i * 2048);
    __builtin_amdgcn_sched_barrier(0);
    // ---- G1: aHi_k0 (4) ----
#pragma unroll
    for (int i = 0; i < 4; ++i) aH[i] = ldf(Ab, aBase + (i + 4) * 2048);
    __builtin_amdgcn_sched_barrier(0);
    stA(kt1, 0, bp ^ 1);
    asm volatile("s_waitcnt lgkmcnt(4)" ::: "memory");  // G0 done
    __builtin_amdgcn_sched_barrier(0);
    __builtin_amdgcn_s_setprio(1);
#pragma unroll
    for (int i = 0; i < 4; ++i)
#pragma unroll
      for (int j = 0; j < 4; ++j)
        acc[i][j] = __builtin_amdgcn_mfma_f32_16x16x32_bf16(b0[j], aL[i],
                                                            acc[i][j], 0, 0, 0);
    __builtin_amdgcn_s_setprio(0);
    __builtin_amdgcn_sched_barrier(0);

    // ---- G2: b_k1 (4) + aLo_k1 (4) (reuse aL regs after last use) ----
#pragma unroll
    for (int j = 0; j < 4; ++j) b1[j] = ldf(Ab, (bBase + j * 2048) ^ 64u);
#pragma unroll
    for (int i = 0; i < 4; ++i) aL[i] = ldf(Ab, (aBase + i * 2048) ^ 64u);
    __builtin_amdgcn_sched_barrier(0);
    stA(kt1, 1, bp ^ 1);
    asm volatile("s_waitcnt lgkmcnt(8)" ::: "memory");  // G1 done
    __builtin_amdgcn_sched_barrier(0);
    __builtin_amdgcn_s_setprio(1);
#pragma unroll
    for (int i = 0; i < 4; ++i)
#pragma unroll
      for (int j = 0; j < 4; ++j)
        acc[i + 4][j] = __builtin_amdgcn_mfma_f32_16x16x32_bf16(b0[j], aH[i],
                                                                acc[i + 4][j],
                                                                0, 0, 0);
    __builtin_amdgcn_s_setprio(0);
    __builtin_amdgcn_sched_barrier(0);

    // ---- G3: aHi_k1 (4) ----
#pragma unroll
    for (int i = 0; i < 4; ++i) aH[i] = ldf(Ab, (aBase + (i + 4) * 2048) ^ 64u);
    __builtin_amdgcn_sched_barrier(0);
    asm volatile("s_waitcnt lgkmcnt(4)" ::: "memory");  // G2 done (b1, aL)
    __builtin_amdgcn_sched_barrier(0);
    // all waves' B reads of buf[bp] complete -> stB may overwrite it
    __builtin_amdgcn_s_barrier();
    __builtin_amdgcn_sched_barrier(0);
    stB(kt2, 0, bp);
    __builtin_amdgcn_s_setprio(1);
#pragma unroll
    for (int i = 0; i < 4; ++i)
#pragma unroll
      for (int j = 0; j < 4; ++j)
        acc[i][j] = __builtin_amdgcn_mfma_f32_16x16x32_bf16(b1[j], aL[i],
                                                            acc[i][j], 0, 0, 0);
    __builtin_amdgcn_s_setprio(0);
    __builtin_amdgcn_sched_barrier(0);

    // ---- P3 ----
    stB(kt2, 1, bp);
    asm volatile("s_waitcnt lgkmcnt(0)" ::: "memory");  // G3 done
    __builtin_amdgcn_sched_barrier(0);
    __builtin_amdgcn_s_setprio(1);
#pragma unroll
    for (int i = 0; i < 4; ++i)
#pragma unroll
      for (int j = 0; j < 4; ++j)
        acc[i + 4][j] = __builtin_amdgcn_mfma_f32_16x16x32_bf16(b1[j], aH[i],
                                                                acc[i + 4][j],
                                                                0, 0, 0);
    __builtin_amdgcn_s_setprio(0);
    __builtin_amdgcn_sched_barrier(0);
    // Tile t+1 fully landed once all-but-4 loads retire (the 4 newest =
    // t+2's B0,B1 stay in flight across the barrier).
    asm volatile("s_waitcnt vmcnt(4)" ::: "memory");
    __builtin_amdgcn_s_barrier();
    __builtin_amdgcn_sched_barrier(0);
  }
  asm volatile("s_waitcnt vmcnt(0)" ::: "memory");  // drain before exit

  // ---- epilogue ----
#pragma unroll
  for (int i = 0; i < 8; ++i) {
    const int trow = m0 + wr * 128 + i * 16 + fr;
    const float2 wt = wtok[trow];
    const float ws = sel ? wt.y : wt.x;
#pragma unroll
    for (int j = 0; j < 4; ++j) {
      const int col0 = n0 + wc * 64 + j * 16 + qw * 4;
      const float4 bb = *reinterpret_cast<const float4*>(bias + col0);
      f32x4 a = acc[i][j];
      if (MODE == 0) {
        u16* C = (u16*)Cv;
        ushort4 o;
        o.x = f2b(gelu_f(a.x + bb.x) * ws);
        o.y = f2b(gelu_f(a.y + bb.y) * ws);
        o.z = f2b(gelu_f(a.z + bb.z) * ws);
        o.w = f2b(gelu_f(a.w + bb.w) * ws);
        *reinterpret_cast<ushort4*>(C + (size_t)trow * N + col0) = o;
      } else {
        float* C = (float*)Cv;
        float4 o;
        o.x = a.x + ws * bb.x;
        o.y = a.y + ws * bb.y;
        o.z = a.z + ws * bb.z;
        o.w = a.w + ws * bb.w;
        if (MODE == 2) {
          float4 pv = *reinterpret_cast<const float4*>(C + (size_t)trow * N + col0);
          o.x += pv.x; o.y += pv.y; o.z += pv.z; o.w += pv.w;
        }
        *reinterpret_cast<float4*>(C + (size_t)trow * N + col0) = o;
      }
    }
  }
}

extern "C" void kernel_launch(void* const* d_in, const int* in_sizes, int n_in,
                              void* d_out, int out_size, void* d_ws, size_t ws_size,
                              hipStream_t stream) {
  const float* x    = (const float*)d_in[0];
  const int*   eid  = (const int*)d_in[1];
  const float* topw = (const float*)d_in[2];
  const float* W1_0 = (const float*)d_in[3];
  const float* b1_0 = (const float*)d_in[4];
  const float* W2_0 = (const float*)d_in[5];
  const float* b2_0 = (const float*)d_in[6];
  const float* W1_1 = (const float*)d_in[7];
  const float* b1_1 = (const float*)d_in[8];
  const float* W2_1 = (const float*)d_in[9];
  const float* b2_1 = (const float*)d_in[10];
  float* out = (float*)d_out;

  char* ws = (char*)d_ws;
  const size_t SZ_WT = (size_t)DM * DF * sizeof(u16);  // 32 MiB
  size_t off = (size_t)NT * sizeof(float2);            // 64 KiB
  float2* wtok = (float2*)ws;
  u16* Xb  = (u16*)(ws + off); off += (size_t)NT * DM * sizeof(u16);  // 32 MiB
  u16* WTa = (u16*)(ws + off); off += SZ_WT;                           // 32 MiB
  u16* WTb = (u16*)(ws + off); off += SZ_WT;                           // 32 MiB
  u16* H   = (u16*)(ws + off); off += (size_t)NT * DF * sizeof(u16);  // 128 MiB

  if (ws_size < off) {
    fill_sentinel<<<(out_size + 255) / 256, 256, 0, stream>>>(out, out_size);
    return;
  }

  prep_wtok<<<(NT + 255) / 256, 256, 0, stream>>>(eid, topw, wtok, NT);
  conv_f32_bf16<<<(NT * DM / 4 + 255) / 256, 256, 0, stream>>>(x, Xb, NT * DM / 4);

  dim3 g1(DF / 256, NT / 256);  // (32, 32) = 1024 wg -> 4 clean rounds @1/CU
  dim3 g2(DM / 256, NT / 256);  // (8, 32)  = 256 wg  -> 1 clean round

  // expert 0
  transpose_conv<<<dim3(DF / 64, DM / 64), 256, 0, stream>>>(W1_0, WTa, DM, DF);
  gemm_bt<0><<<g1, 512, 0, stream>>>(Xb, WTa, H, wtok, b1_0, NT, DF, DM, 0);
  transpose_conv<<<dim3(DM / 64, DF / 64), 256, 0, stream>>>(W2_0, WTb, DF, DM);
  gemm_bt<1><<<g2, 512, 0, stream>>>(H, WTb, out, wtok, b2_0, NT, DM, DF, 0);
  // expert 1
  transpose_conv<<<dim3(DF / 64, DM / 64), 256, 0, stream>>>(W1_1, WTa, DM, DF);
  gemm_bt<0><<<g1, 512, 0, stream>>>(Xb, WTa, H, wtok, b1_1, NT, DF, DM, 1);
  transpose_conv<<<dim3(DM / 64, DF / 64), 256, 0, stream>>>(W2_1, WTb, DF, DM);
  gemm_bt<2><<<g2, 512, 0, stream>>>(H, WTb, out, wtok, b2_1, NT, DM, DF, 1);
}

// Round 5
// 1231.213 us; speedup vs baseline: 1.1607x; 1.0063x over previous
//
#include <hip/hip_runtime.h>
#include <hip/hip_bf16.h>
#include <stdint.h>

#define DM 2048
#define DF 8192
#define NT 8192

typedef unsigned short u16;
typedef __attribute__((ext_vector_type(8))) __bf16 bf16x8;
typedef __attribute__((ext_vector_type(4))) float f32x4;

typedef __attribute__((address_space(1))) uint8_t ga_u8_t;
typedef __attribute__((address_space(3))) uint8_t lds_u8_t;

__device__ __forceinline__ void async_cp16(const void* g, void* l) {
  __builtin_amdgcn_global_load_lds((ga_u8_t*)g, (lds_u8_t*)l, 16, 0, 0);
}

__device__ __forceinline__ u16 f2b(float f) {
  unsigned int u = __builtin_bit_cast(unsigned int, f);
  u = (u + 0x7fffu + ((u >> 16) & 1u)) >> 16;
  return (u16)u;
}

// Branch-free erf (A&S 7.1.26, |err|<=1.5e-7). H is bf16-rounded (rel 2^-9),
// so the approximation error is invisible. ~14 VALU inst, no divergence.
__device__ __forceinline__ float erf_fast(float z) {
  float az = fabsf(z);
  float t = __builtin_amdgcn_rcpf(fmaf(0.3275911f, az, 1.0f));
  float p = t * fmaf(t, fmaf(t, fmaf(t, fmaf(t, 1.061405429f, -1.453152027f),
                                     1.421413741f), -0.284496736f),
                     0.254829592f);
  float r = fmaf(-p, __expf(-az * az), 1.0f);
  return copysignf(r, z);
}
__device__ __forceinline__ float gelu_f(float x) {
  return 0.5f * x * (1.0f + erf_fast(x * 0.70710678118654752f));
}

// -------- per-token combined gate weights: wtok[t] = (w0_eff, w1_eff) --------
__global__ void prep_wtok(const int* __restrict__ eid, const float* __restrict__ w,
                          float2* __restrict__ wtok, int n) {
  int i = blockIdx.x * blockDim.x + threadIdx.x;
  if (i >= n) return;
  float a = 0.f, b = 0.f;
  int e0 = eid[2 * i] & 1, e1 = eid[2 * i + 1] & 1;
  float w0 = w[2 * i], w1 = w[2 * i + 1];
  if (e0) b += w0; else a += w0;
  if (e1) b += w1; else a += w1;
  wtok[i] = make_float2(a, b);
}

// -------- fp32 -> bf16 elementwise (x -> Xb) --------
__global__ void conv_f32_bf16(const float* __restrict__ in, u16* __restrict__ out,
                              int n4) {
  int i = blockIdx.x * blockDim.x + threadIdx.x;
  if (i >= n4) return;
  float4 v = reinterpret_cast<const float4*>(in)[i];
  ushort4 o;
  o.x = f2b(v.x); o.y = f2b(v.y); o.z = f2b(v.z); o.w = f2b(v.w);
  reinterpret_cast<ushort4*>(out)[i] = o;
}

// -------- fp32 transpose+convert: in (R x Cc) fp32 -> out (Cc x R) bf16 -----
// 64x64 tile, float4 global loads, ushort4 stores in 128B runs per 16 lanes.
__global__ void transpose_conv(const float* __restrict__ in, u16* __restrict__ out,
                               int R, int Cc) {
  __shared__ float tile[64][65];
  const int tid = threadIdx.x;          // 256 threads
  const int r0 = blockIdx.y * 64, c0 = blockIdx.x * 64;
  const int ty = tid >> 4;              // 0..15
  const int tx = (tid & 15) << 2;       // 0,4,..,60
#pragma unroll
  for (int i = 0; i < 4; ++i) {
    int r = ty + i * 16;
    float4 v = *reinterpret_cast<const float4*>(&in[(size_t)(r0 + r) * Cc + c0 + tx]);
    tile[r][tx] = v.x; tile[r][tx + 1] = v.y;
    tile[r][tx + 2] = v.z; tile[r][tx + 3] = v.w;
  }
  __syncthreads();
  const int rg = (tid & 15) << 2;       // output r = rg..rg+3
  const int cg = tid >> 4;              // output c = cg + 16*i
#pragma unroll
  for (int i = 0; i < 4; ++i) {
    int c = cg + 16 * i;
    ushort4 o;
    o.x = f2b(tile[rg + 0][c]);
    o.y = f2b(tile[rg + 1][c]);
    o.z = f2b(tile[rg + 2][c]);
    o.w = f2b(tile[rg + 3][c]);
    *reinterpret_cast<ushort4*>(&out[(size_t)(c0 + c) * R + r0 + rg]) = o;
  }
}

__global__ void fill_sentinel(float* p, int n) {
  int i = blockIdx.x * blockDim.x + threadIdx.x;
  if (i < n) p[i] = 0.125f;
}

// ============================================================================
// 256x256-tile, BK=64, 8-wave (2Mx4N) GEMM. ONE barrier per K-tile.
// B is TRIPLE-buffered (3 x 32 KB): tile t reads Bbuf[t%3], stB(t+2) writes
// Bbuf[(t+2)%3] == the buffer last read at tile t-1, whose reads completed
// before the t-1 end-barrier -> the single tile-end barrier orders everything
// (A dbuf unchanged at 2 x 32 KB). LDS total = 160 KB (gfx950 per-WG max;
// we were already 1 block/CU at 128 KB, so no occupancy loss).
// k-split 4-phase schedule with one-group-ahead ds_read prefetch and counted
// lgkmcnt (FIFO: G0{b0,aL}=8, G1{aH}=4 -> lgkm(4); G2{b1,aL'}=8 -> lgkm(8);
// G3{aH'}=4 -> lgkm(4); -> lgkm(0)). vmcnt(4) once per tile: t+2's B stays
// in flight across the barrier (8 VMEM issues/tile, retire A(t+1)+B(t+1)).
// vmcnt ledger: prologue issues 12, vmcnt(4) leaves B(1) in flight; each
// tile issues 8, vmcnt(4) retires exactly A(t+1)+B(t+1). Tail kt1/kt2
// clamps restage into dead buffers (counts stay uniform).
// MODE 0: C(bf16) = bf16( gelu(acc + bias[col]) * w_eff[t] )   (GEMM1 -> H)
// MODE 1: C(f32)  = acc + w_eff[t]*bias[col]                   (GEMM2, e0)
// MODE 2: C(f32) += acc + w_eff[t]*bias[col]                   (GEMM2, e1)
// ============================================================================
template <int MODE>
__global__ __launch_bounds__(512, 2)
void gemm_bt(const u16* __restrict__ A, const u16* __restrict__ Bt,
             void* __restrict__ Cv, const float2* __restrict__ wtok,
             const float* __restrict__ bias,
             int M, int N, int K, int sel) {
  __shared__ __align__(16) char smem[163840];  // A: 2x32K @0,32K; B: 3x32K @64K..
  const int tid = threadIdx.x;
  const int w = tid >> 6;
  const int lane = tid & 63;

  // ---- bijective XCD swizzle (all our grids have nwg % 8 == 0) ----
  const int nwg = gridDim.x * gridDim.y;
  const int wg = blockIdx.y * gridDim.x + blockIdx.x;
  const int swz = (wg & 7) * (nwg >> 3) + (wg >> 3);
  const int bx = swz % gridDim.x;
  const int by = swz / gridDim.x;
  const int m0 = by * 256;
  const int n0 = bx * 256;
  const int NKT = K >> 6;

  // ---- staging addresses: wave-uniform LDS base + lane*16 (m104) ----
  const int r8 = lane >> 3, p8 = lane & 7, q = p8 ^ r8;
  const u16* gA[2];
  const u16* gB[2];
  int ldsOff[2];
#pragma unroll
  for (int j = 0; j < 2; ++j) {
    const int c = j * 8 + w;          // chunk 0..15 within a 128-row half
    const int row = c * 8 + r8;
    gA[j] = A + (size_t)(m0 + row) * K + q * 8;
    gB[j] = Bt + (size_t)(n0 + row) * K + q * 8;
    ldsOff[j] = c * 1024;
  }
  const size_t hstep = (size_t)128 * K;

  auto stA = [&](int kt, int h, int bp) {    // bp in {0,1} -> byte 0 / 32768
    char* d = smem + bp * 32768 + h * 16384;
    const size_t go = (size_t)h * hstep + (size_t)kt * 64;
    async_cp16(gA[0] + go, d + ldsOff[0]);
    async_cp16(gA[1] + go, d + ldsOff[1]);
  };
  auto stB = [&](int kt, int h, int bbase) {  // bbase = absolute byte offset
    char* d = smem + bbase + h * 16384;
    const size_t go = (size_t)h * hstep + (size_t)kt * 64;
    async_cp16(gB[0] + go, d + ldsOff[0]);
    async_cp16(gB[1] + go, d + ldsOff[1]);
  };

  // ---- fragment read bases (k1 is addr ^ 64: slot bit2 == logical k+4) ----
  const int fr = lane & 15, qw = lane >> 4;
  const int wr = w >> 2, wc = w & 3;     // wave -> 128x64 output sub-tile
  const int sw = (qw ^ (fr & 7)) << 4;
  const uint32_t aBase = (uint32_t)((wr * 128 + fr) * 128 + sw);
  const uint32_t bRel = (uint32_t)((wc * 64 + fr) * 128 + sw);  // + B buf base

  auto ldf = [&](const char* base, uint32_t off) {
    return *reinterpret_cast<const bf16x8*>(base + off);
  };

  f32x4 acc[8][4] = {};
  bf16x8 aL[4], aH[4], b0[4], b1[4];

  // ---- prologue: A(0)->Abuf0, B(0)->Bbuf0, B(1)->Bbuf1; counted wait ----
  stA(0, 0, 0); stA(0, 1, 0);
  stB(0, 0, 65536); stB(0, 1, 65536);
  stB(1, 0, 98304); stB(1, 1, 98304);
  asm volatile("s_waitcnt vmcnt(4)" ::: "memory");
  __builtin_amdgcn_s_barrier();
  __builtin_amdgcn_sched_barrier(0);

  int bRead = 65536;      // B buffer being read this tile   (t%3)
  int bWrite = 131072;    // B buffer stB targets this tile  ((t+2)%3)

  for (int t = 0; t < NKT; ++t) {
    const int bp = t & 1;
    const char* Ab = smem + bp * 32768;
    const char* Bb = smem + bRead;
    const int kt1 = (t + 1 < NKT) ? t + 1 : NKT - 1;  // clamp: keeps issue
    const int kt2 = (t + 2 < NKT) ? t + 2 : NKT - 1;  // count & vmcnt uniform

    // ---- G0: b_k0 (4) + aLo_k0 (4) ----
#pragma unroll
    for (int j = 0; j < 4; ++j) b0[j] = ldf(Bb, bRel + j * 2048);
#pragma unroll
    for (int i = 0; i < 4; ++i) aL[i] = ldf(Ab, aBase + i * 2048);
    __builtin_amdgcn_sched_barrier(0);
    // ---- G1: aHi_k0 (4) ----
#pragma unroll
    for (int i = 0; i < 4; ++i) aH[i] = ldf(Ab, aBase + (i + 4) * 2048);
    __builtin_amdgcn_sched_barrier(0);
    stA(kt1, 0, bp ^ 1);
    asm volatile("s_waitcnt lgkmcnt(4)" ::: "memory");  // G0 done
    __builtin_amdgcn_sched_barrier(0);
    __builtin_amdgcn_s_setprio(1);
#pragma unroll
    for (int i = 0; i < 4; ++i)
#pragma unroll
      for (int j = 0; j < 4; ++j)
        acc[i][j] = __builtin_amdgcn_mfma_f32_16x16x32_bf16(b0[j], aL[i],
                                                            acc[i][j], 0, 0, 0);
    __builtin_amdgcn_s_setprio(0);
    __builtin_amdgcn_sched_barrier(0);

    // ---- G2: b_k1 (4) + aLo_k1 (4) (reuse aL regs after last use) ----
#pragma unroll
    for (int j = 0; j < 4; ++j) b1[j] = ldf(Bb, (bRel + j * 2048) ^ 64u);
#pragma unroll
    for (int i = 0; i < 4; ++i) aL[i] = ldf(Ab, (aBase + i * 2048) ^ 64u);
    __builtin_amdgcn_sched_barrier(0);
    stA(kt1, 1, bp ^ 1);
    asm volatile("s_waitcnt lgkmcnt(8)" ::: "memory");  // G1 done
    __builtin_amdgcn_sched_barrier(0);
    __builtin_amdgcn_s_setprio(1);
#pragma unroll
    for (int i = 0; i < 4; ++i)
#pragma unroll
      for (int j = 0; j < 4; ++j)
        acc[i + 4][j] = __builtin_amdgcn_mfma_f32_16x16x32_bf16(b0[j], aH[i],
                                                                acc[i + 4][j],
                                                                0, 0, 0);
    __builtin_amdgcn_s_setprio(0);
    __builtin_amdgcn_sched_barrier(0);

    // ---- G3: aHi_k1 (4); stage t+2 B-half0 (triple-buffer: no barrier) ----
#pragma unroll
    for (int i = 0; i < 4; ++i) aH[i] = ldf(Ab, (aBase + (i + 4) * 2048) ^ 64u);
    __builtin_amdgcn_sched_barrier(0);
    stB(kt2, 0, bWrite);
    asm volatile("s_waitcnt lgkmcnt(4)" ::: "memory");  // G2 done (b1, aL)
    __builtin_amdgcn_sched_barrier(0);
    __builtin_amdgcn_s_setprio(1);
#pragma unroll
    for (int i = 0; i < 4; ++i)
#pragma unroll
      for (int j = 0; j < 4; ++j)
        acc[i][j] = __builtin_amdgcn_mfma_f32_16x16x32_bf16(b1[j], aL[i],
                                                            acc[i][j], 0, 0, 0);
    __builtin_amdgcn_s_setprio(0);
    __builtin_amdgcn_sched_barrier(0);

    // ---- P3 ----
    stB(kt2, 1, bWrite);
    asm volatile("s_waitcnt lgkmcnt(0)" ::: "memory");  // G3 done
    __builtin_amdgcn_sched_barrier(0);
    __builtin_amdgcn_s_setprio(1);
#pragma unroll
    for (int i = 0; i < 4; ++i)
#pragma unroll
      for (int j = 0; j < 4; ++j)
        acc[i + 4][j] = __builtin_amdgcn_mfma_f32_16x16x32_bf16(b1[j], aH[i],
                                                                acc[i + 4][j],
                                                                0, 0, 0);
    __builtin_amdgcn_s_setprio(0);
    __builtin_amdgcn_sched_barrier(0);
    // Tile t+1 fully landed once all-but-4 loads retire (the 4 newest =
    // t+2's B0,B1 stay in flight across the barrier).
    asm volatile("s_waitcnt vmcnt(4)" ::: "memory");
    __builtin_amdgcn_s_barrier();
    __builtin_amdgcn_sched_barrier(0);

    // rotate B buffers: next write target = buffer just read (t-1 pattern)
    bWrite = bRead;
    bRead = (bRead == 131072) ? 65536 : bRead + 32768;
  }
  asm volatile("s_waitcnt vmcnt(0)" ::: "memory");  // drain before exit

  // ---- epilogue ----
#pragma unroll
  for (int i = 0; i < 8; ++i) {
    const int trow = m0 + wr * 128 + i * 16 + fr;
    const float2 wt = wtok[trow];
    const float ws = sel ? wt.y : wt.x;
#pragma unroll
    for (int j = 0; j < 4; ++j) {
      const int col0 = n0 + wc * 64 + j * 16 + qw * 4;
      const float4 bb = *reinterpret_cast<const float4*>(bias + col0);
      f32x4 a = acc[i][j];
      if (MODE == 0) {
        u16* C = (u16*)Cv;
        ushort4 o;
        o.x = f2b(gelu_f(a.x + bb.x) * ws);
        o.y = f2b(gelu_f(a.y + bb.y) * ws);
        o.z = f2b(gelu_f(a.z + bb.z) * ws);
        o.w = f2b(gelu_f(a.w + bb.w) * ws);
        *reinterpret_cast<ushort4*>(C + (size_t)trow * N + col0) = o;
      } else {
        float* C = (float*)Cv;
        float4 o;
        o.x = a.x + ws * bb.x;
        o.y = a.y + ws * bb.y;
        o.z = a.z + ws * bb.z;
        o.w = a.w + ws * bb.w;
        if (MODE == 2) {
          float4 pv = *reinterpret_cast<const float4*>(C + (size_t)trow * N + col0);
          o.x += pv.x; o.y += pv.y; o.z += pv.z; o.w += pv.w;
        }
        *reinterpret_cast<float4*>(C + (size_t)trow * N + col0) = o;
      }
    }
  }
}

extern "C" void kernel_launch(void* const* d_in, const int* in_sizes, int n_in,
                              void* d_out, int out_size, void* d_ws, size_t ws_size,
                              hipStream_t stream) {
  const float* x    = (const float*)d_in[0];
  const int*   eid  = (const int*)d_in[1];
  const float* topw = (const float*)d_in[2];
  const float* W1_0 = (const float*)d_in[3];
  const float* b1_0 = (const float*)d_in[4];
  const float* W2_0 = (const float*)d_in[5];
  const float* b2_0 = (const float*)d_in[6];
  const float* W1_1 = (const float*)d_in[7];
  const float* b1_1 = (const float*)d_in[8];
  const float* W2_1 = (const float*)d_in[9];
  const float* b2_1 = (const float*)d_in[10];
  float* out = (float*)d_out;

  char* ws = (char*)d_ws;
  const size_t SZ_WT = (size_t)DM * DF * sizeof(u16);  // 32 MiB
  size_t off = (size_t)NT * sizeof(float2);            // 64 KiB
  float2* wtok = (float2*)ws;
  u16* Xb  = (u16*)(ws + off); off += (size_t)NT * DM * sizeof(u16);  // 32 MiB
  u16* WTa = (u16*)(ws + off); off += SZ_WT;                           // 32 MiB
  u16* WTb = (u16*)(ws + off); off += SZ_WT;                           // 32 MiB
  u16* H   = (u16*)(ws + off); off += (size_t)NT * DF * sizeof(u16);  // 128 MiB

  if (ws_size < off) {
    fill_sentinel<<<(out_size + 255) / 256, 256, 0, stream>>>(out, out_size);
    return;
  }

  prep_wtok<<<(NT + 255) / 256, 256, 0, stream>>>(eid, topw, wtok, NT);
  conv_f32_bf16<<<(NT * DM / 4 + 255) / 256, 256, 0, stream>>>(x, Xb, NT * DM / 4);

  dim3 g1(DF / 256, NT / 256);  // (32, 32) = 1024 wg -> 4 clean rounds @1/CU
  dim3 g2(DM / 256, NT / 256);  // (8, 32)  = 256 wg  -> 1 clean round

  // expert 0
  transpose_conv<<<dim3(DF / 64, DM / 64), 256, 0, stream>>>(W1_0, WTa, DM, DF);
  gemm_bt<0><<<g1, 512, 0, stream>>>(Xb, WTa, H, wtok, b1_0, NT, DF, DM, 0);
  transpose_conv<<<dim3(DM / 64, DF / 64), 256, 0, stream>>>(W2_0, WTb, DF, DM);
  gemm_bt<1><<<g2, 512, 0, stream>>>(H, WTb, out, wtok, b2_0, NT, DM, DF, 0);
  // expert 1
  transpose_conv<<<dim3(DF / 64, DM / 64), 256, 0, stream>>>(W1_1, WTa, DM, DF);
  gemm_bt<0><<<g1, 512, 0, stream>>>(Xb, WTa, H, wtok, b1_1, NT, DF, DM, 1);
  transpose_conv<<<dim3(DM / 64, DF / 64), 256, 0, stream>>>(W2_1, WTb, DF, DM);
  gemm_bt<2><<<g2, 512, 0, stream>>>(H, WTb, out, wtok, b2_1, NT, DM, DF, 1);
}